// Round 1
// baseline (23538.727 us; speedup 1.0000x reference)
//
#include <hip/hip_runtime.h>
#include <hip/hip_bf16.h>

#define SLEN 2048
#define BDIM 64
#define IDIM 512
#define HDIM 512
#define GDIM 2048   // 4H
#define KTOT 1024   // I + H
#define NWG  64

typedef __bf16 bf16x8 __attribute__((ext_vector_type(8)));
typedef float  f32x4  __attribute__((ext_vector_type(4)));

__device__ inline unsigned short f2bf(float f) {
  union { float f; unsigned u; } v; v.f = f;
  unsigned r = v.u + 0x7FFFu + ((v.u >> 16) & 1u);
  return (unsigned short)(r >> 16);
}

__device__ inline unsigned long long pack4bf(float f0, float f1, float f2, float f3) {
  return (unsigned long long)f2bf(f0) | ((unsigned long long)f2bf(f1) << 16)
       | ((unsigned long long)f2bf(f2) << 32) | ((unsigned long long)f2bf(f3) << 48);
}

__device__ inline float sigm(float x) {
  return __builtin_amdgcn_rcpf(1.f + __expf(-x));
}
__device__ inline float tanh_f(float x) {
  float e = __expf(2.f * x);
  return 1.f - 2.f * __builtin_amdgcn_rcpf(e + 1.f);
}

// CT[row][k], row = w*32 + gate*8 + moff  ->  j = gate*512 + w*8 + moff
// k < 512: W[k][j] ; k >= 512: U[k-512][j]
__global__ __launch_bounds__(256) void prep_ct(const float* __restrict__ W,
                                               const float* __restrict__ U,
                                               unsigned short* __restrict__ CT) {
  int row = blockIdx.x;
  int w = row >> 5, within = row & 31;
  int gate = within >> 3, moff = within & 7;
  int j = gate * HDIM + w * 8 + moff;
  for (int k = threadIdx.x; k < KTOT; k += 256) {
    float v = (k < IDIM) ? W[(size_t)k * GDIM + j] : U[(size_t)(k - IDIM) * GDIM + j];
    CT[(size_t)row * KTOT + k] = f2bf(v);
  }
}

__device__ inline void gbar(unsigned* flags, int w, int wid, int lane, unsigned gen) {
  __syncthreads();                 // drains each thread's stores (vmcnt 0) before release
  if (wid == 0) {
    if (lane == 0)
      __hip_atomic_store(flags + (size_t)w * 32, gen, __ATOMIC_RELEASE,
                         __HIP_MEMORY_SCOPE_AGENT);
    unsigned v;
    do {
      v = __hip_atomic_load(flags + (size_t)lane * 32, __ATOMIC_RELAXED,
                            __HIP_MEMORY_SCOPE_AGENT);
    } while (v < gen);
  }
  __syncthreads();
  __threadfence();                 // acquire: invalidate stale L1/L2 before reading xh
}

__global__ __launch_bounds__(256, 1) void lstm_persist(
    const float* __restrict__ x, const float* __restrict__ bias,
    const unsigned short* __restrict__ CT,
    unsigned short* __restrict__ xh, unsigned* __restrict__ flags,
    float* __restrict__ out) {
  const int w    = blockIdx.x;          // 0..63, owns H-cols [8w, 8w+8)
  const int tid  = threadIdx.x;
  const int lane = tid & 63;
  const int wid  = tid >> 6;            // 0..3
  const int r    = wid & 1;             // row half: rows [32r, 32r+32)
  const int kh   = wid >> 1;            // K half: k in [512*kh, 512*kh+512)
  const int lg   = lane >> 4;           // 0..3
  const int lc   = lane & 15;           // col within tile

  __shared__ float lds_part[2][64][16]; // [r][lane][4 tiles x 4 regs]

  // ---- step-invariant B fragments (weights) cached in 128 VGPRs ----
  bf16x8 Bf[2][16];
  {
    const unsigned short* ctb = CT + (size_t)(w * 32) * KTOT;
    #pragma unroll
    for (int nt = 0; nt < 2; ++nt)
      #pragma unroll
      for (int kk = 0; kk < 16; ++kk) {
        const unsigned short* p =
            ctb + (size_t)(nt * 16 + lc) * KTOT + kh * 512 + kk * 32 + lg * 8;
        Bf[nt][kk] = *(const bf16x8*)p;
      }
  }

  const int mcol = w * 8 + (lc & 7);
  const float b_i = bias[mcol];
  const float b_f = bias[HDIM + mcol];
  const float b_g = bias[2 * HDIM + mcol];
  const float b_o = bias[3 * HDIM + mcol];

  float cst[4] = {0.f, 0.f, 0.f, 0.f};  // c-state: 4 (b,m) cells per lane (kh==0 waves)

  // ---- init xh buffer 0, row b = w: x-part = bf16(x[0][w][:]), h-part = 0 ----
  {
    int k0 = tid * 4;
    unsigned long long v = 0ull;
    if (k0 < IDIM) {
      f32x4 xv = *(const f32x4*)(x + (size_t)w * IDIM + k0);
      v = pack4bf(xv[0], xv[1], xv[2], xv[3]);
    }
    *(unsigned long long*)(xh + (size_t)w * KTOT + k0) = v;
  }

  unsigned gen = 1;
  gbar(flags, w, wid, lane, gen); ++gen;

  const size_t HS = (size_t)SLEN * BDIM * HDIM;

  for (int t = 0; t < SLEN; ++t) {
    const unsigned short* cur = xh + (size_t)(t & 1) * BDIM * KTOT;
    unsigned short*       nxt = xh + (size_t)((t + 1) & 1) * BDIM * KTOT;

    // ---- GEMM: gates[rows 32r..+32][32 cols] over K-half kh ----
    f32x4 acc00 = {0.f,0.f,0.f,0.f}, acc01 = {0.f,0.f,0.f,0.f};
    f32x4 acc10 = {0.f,0.f,0.f,0.f}, acc11 = {0.f,0.f,0.f,0.f};
    const unsigned short* ab = cur + (size_t)(r * 32 + lc) * KTOT + kh * 512 + lg * 8;
    #pragma unroll
    for (int kk = 0; kk < 16; ++kk) {
      bf16x8 a0 = *(const bf16x8*)(ab + kk * 32);
      bf16x8 a1 = *(const bf16x8*)(ab + 16 * KTOT + kk * 32);
      acc00 = __builtin_amdgcn_mfma_f32_16x16x32_bf16(a0, Bf[0][kk], acc00, 0, 0, 0);
      acc01 = __builtin_amdgcn_mfma_f32_16x16x32_bf16(a0, Bf[1][kk], acc01, 0, 0, 0);
      acc10 = __builtin_amdgcn_mfma_f32_16x16x32_bf16(a1, Bf[0][kk], acc10, 0, 0, 0);
      acc11 = __builtin_amdgcn_mfma_f32_16x16x32_bf16(a1, Bf[1][kk], acc11, 0, 0, 0);
    }

    // ---- K-half reduction through LDS ----
    if (kh == 1) {
      f32x4* dst = (f32x4*)&lds_part[r][lane][0];
      dst[0] = acc00; dst[1] = acc01; dst[2] = acc10; dst[3] = acc11;
    }
    __syncthreads();

    if (kh == 0) {
      const f32x4* src = (const f32x4*)&lds_part[r][lane][0];
      acc00 += src[0]; acc01 += src[1]; acc10 += src[2]; acc11 += src[3];

      // cols layout: tile0 = [i(0..7) f(0..7)], tile1 = [g(0..7) o(0..7)]
      const bool hi = lc >= 8;
      const size_t outbase = (size_t)t * (BDIM * HDIM);
      #pragma unroll
      for (int reg = 0; reg < 4; ++reg) {
        float a00 = acc00[reg], a01 = acc01[reg];
        float a10 = acc10[reg], a11 = acc11[reg];
        float e00 = __shfl_xor(a00, 8, 64);
        float e01 = __shfl_xor(a01, 8, 64);
        float e10 = __shfl_xor(a10, 8, 64);
        float e11 = __shfl_xor(a11, 8, 64);
        // lane lo handles row-tile mt=0, lane hi handles mt=1
        float gi = hi ? e10 : a00;
        float gf = hi ? a10 : e00;
        float gg = hi ? e11 : a01;
        float go = hi ? a11 : e01;
        float it = sigm(gi + b_i);
        float ft = sigm(gf + b_f);
        float gt = tanh_f(gg + b_g);
        float ot = sigm(go + b_o);
        float cn = ft * cst[reg] + it * gt;
        cst[reg] = cn;
        float hn = ot * tanh_f(cn);
        int b = r * 32 + (hi ? 16 : 0) + lg * 4 + reg;
        out[outbase + (size_t)b * HDIM + mcol] = hn;
        nxt[(size_t)b * KTOT + IDIM + mcol] = f2bf(hn);
        if (t == SLEN - 1) {
          out[HS + (size_t)b * HDIM + mcol] = hn;                    // h_t
          out[HS + (size_t)BDIM * HDIM + (size_t)b * HDIM + mcol] = cn; // c_t
        }
      }
    } else if (t + 1 < SLEN) {
      // kh==1 waves: convert x[t+1][w][:] to bf16 into next buffer
      int lt = tid - 128;  // 0..127
      const float* xr = x + ((size_t)(t + 1) * BDIM + w) * IDIM + lt * 4;
      f32x4 xv = *(const f32x4*)xr;
      *(unsigned long long*)(nxt + (size_t)w * KTOT + lt * 4) =
          pack4bf(xv[0], xv[1], xv[2], xv[3]);
    }

    gbar(flags, w, wid, lane, gen); ++gen;
  }
}

extern "C" void kernel_launch(void* const* d_in, const int* in_sizes, int n_in,
                              void* d_out, int out_size, void* d_ws, size_t ws_size,
                              hipStream_t stream) {
  const float* x    = (const float*)d_in[0];
  const float* W    = (const float*)d_in[1];
  const float* U    = (const float*)d_in[2];
  const float* bias = (const float*)d_in[3];
  float* out = (float*)d_out;

  unsigned short* CT = (unsigned short*)d_ws;                       // 4 MiB
  unsigned short* xh = (unsigned short*)((char*)d_ws + (size_t)GDIM * KTOT * 2); // 256 KiB
  unsigned* flags = (unsigned*)((char*)d_ws + (size_t)GDIM * KTOT * 2
                                            + (size_t)2 * BDIM * KTOT * 2);      // 8 KiB

  hipMemsetAsync(flags, 0, NWG * 32 * sizeof(unsigned), stream);
  prep_ct<<<GDIM, 256, 0, stream>>>(W, U, CT);
  lstm_persist<<<NWG, 256, 0, stream>>>(x, bias, CT, xh, flags, out);
}